// Round 1
// 236.431 us; speedup vs baseline: 1.0041x; 1.0041x over previous
//
#include <hip/hip_runtime.h>

// LinearRNN as truncated FIR convolution:
//   y_t = sum_{i=0}^{32} G_i u_{t-i} + C A^t x0,   G_0 = D, G_i = C A^{i-1} B.
// R3: k_conv restructured around stride-16 tap pairing:
//   a-frag(tap i, mtile mt) == a-frag(tap i+16, mtile mt+1)   (rows differ by 16)
// so taps {j, j+16} share one ds_read_b128 -> 8 MFMA per LDS read (was 4),
// 304 reads/wave (was 528). LDS re-padded to 128 B rows + XOR swizzle
// byte ^= ((row&7)<<4) on write and read (T2/m214-verified pattern for
// [R][128B] row-major bf16 read as b128) -> bank conflicts ~0.

#define T_LEN  262144
#define NTAP   33      // taps 0..32
#define ZLEN   48      // x0-correction horizon
#define ROWS   512     // output rows per conv block
#define HALO   32

typedef __attribute__((ext_vector_type(8))) short  short8;
typedef __attribute__((ext_vector_type(4))) short  short4v;
typedef __attribute__((ext_vector_type(4))) float  floatx4;

static __device__ __forceinline__ unsigned short f2bf(float f) {
    unsigned int x = __float_as_uint(f);
    x += 0x7fffu + ((x >> 16) & 1u);     // RNE (finite normals)
    return (unsigned short)(x >> 16);
}
static __device__ __forceinline__ float bf2f(unsigned short u) {
    return __uint_as_float(((unsigned int)u) << 16);
}

// ---------------------------------------------------------------------------
// K1: UNCHANGED from the verified R2 kernel (no counters yet -> no blind edits).
// Precompute G (bf16, [tap][p][m]) and z_t = C A^t x0 (fp32, t < ZLEN).
// ---------------------------------------------------------------------------
__global__ __launch_bounds__(256, 1) void k_prep(
    const float* __restrict__ A, const float* __restrict__ B,
    const float* __restrict__ C, const float* __restrict__ D,
    const float* __restrict__ x0, unsigned short* __restrict__ gG,
    float* __restrict__ gZ)
{
    __shared__ unsigned short At[64][72];  // At[j][k] = A[k][j]  (b-frags for M@A)
    __shared__ unsigned short Bt[64][72];  // Bt[m][n] = B[n][m]  (b-frags for M@B)
    __shared__ unsigned short M0[64][72];  // M chain ping
    __shared__ unsigned short M1[64][72];  // M chain pong
    const int tid = threadIdx.x;
    const int wv = tid >> 6, lane = tid & 63, l15 = lane & 15, q = lane >> 4;

#pragma unroll
    for (int e = 0; e < 16; ++e) {
        int f = e * 256 + tid;
        int r = f >> 6, cc = f & 63;
        At[cc][r] = f2bf(A[f]);            // transpose
        Bt[cc][r] = f2bf(B[f]);            // transpose
        M0[r][cc] = f2bf(C[f]);            // M_0 = C, natural [p][k]
        gG[f]     = f2bf(D[f]);            // G_0 = D, natural [p][m]
    }
    __syncthreads();

    float x0v[4];
#pragma unroll
    for (int nt = 0; nt < 4; ++nt) x0v[nt] = x0[l15 + 16 * nt];

    short8 bA[2][4], bB[2][4];
#pragma unroll
    for (int kb = 0; kb < 2; ++kb)
#pragma unroll
        for (int nt = 0; nt < 4; ++nt) {
            bA[kb][nt] = *(const short8*)&At[l15 + 16*nt][kb*32 + q*8];
            bB[kb][nt] = *(const short8*)&Bt[l15 + 16*nt][kb*32 + q*8];
        }

#pragma unroll
    for (int r = 0; r < 4; ++r) {
        float v = 0.f;
#pragma unroll
        for (int nt = 0; nt < 4; ++nt)
            v += bf2f(M0[16*wv + q*4 + r][l15 + 16*nt]) * x0v[nt];
        v += __shfl_xor(v, 1, 16); v += __shfl_xor(v, 2, 16);
        v += __shfl_xor(v, 4, 16); v += __shfl_xor(v, 8, 16);
        if (l15 == 0) gZ[16*wv + q*4 + r] = v;
    }

    unsigned short (*Ms)[72] = M0;
    unsigned short (*Md)[72] = M1;
    for (int i = 1; i < ZLEN; ++i) {
        short8 a0 = *(const short8*)&Ms[16*wv + l15][q*8];        // kb=0
        short8 a1 = *(const short8*)&Ms[16*wv + l15][32 + q*8];   // kb=1

        if (i < NTAP) {                    // G_i = M_{i-1} @ B
            floatx4 g[4];
#pragma unroll
            for (int nt = 0; nt < 4; ++nt) {
                g[nt] = (floatx4){0.f, 0.f, 0.f, 0.f};
                g[nt] = __builtin_amdgcn_mfma_f32_16x16x32_bf16(a0, bB[0][nt], g[nt], 0, 0, 0);
                g[nt] = __builtin_amdgcn_mfma_f32_16x16x32_bf16(a1, bB[1][nt], g[nt], 0, 0, 0);
            }
#pragma unroll
            for (int nt = 0; nt < 4; ++nt)
#pragma unroll
                for (int r = 0; r < 4; ++r)
                    gG[(size_t)i*4096 + (16*wv + q*4 + r)*64 + l15 + 16*nt] = f2bf(g[nt][r]);
        }

        floatx4 m[4];
#pragma unroll
        for (int nt = 0; nt < 4; ++nt) {
            m[nt] = (floatx4){0.f, 0.f, 0.f, 0.f};
            m[nt] = __builtin_amdgcn_mfma_f32_16x16x32_bf16(a0, bA[0][nt], m[nt], 0, 0, 0);
            m[nt] = __builtin_amdgcn_mfma_f32_16x16x32_bf16(a1, bA[1][nt], m[nt], 0, 0, 0);
        }
#pragma unroll
        for (int nt = 0; nt < 4; ++nt)
#pragma unroll
            for (int r = 0; r < 4; ++r)
                Md[16*wv + q*4 + r][l15 + 16*nt] = f2bf(m[nt][r]);

#pragma unroll
        for (int r = 0; r < 4; ++r) {
            float v = 0.f;
#pragma unroll
            for (int nt = 0; nt < 4; ++nt) v = fmaf(m[nt][r], x0v[nt], v);
            v += __shfl_xor(v, 1, 16); v += __shfl_xor(v, 2, 16);
            v += __shfl_xor(v, 4, 16); v += __shfl_xor(v, 8, 16);
            if (l15 == 0) gZ[i*64 + 16*wv + q*4 + r] = v;
        }

        unsigned short (*tmp)[72] = Ms; Ms = Md; Md = tmp;
    }
}

// ---------------------------------------------------------------------------
// K2: the convolution, tap-paired + swizzled.
// Block: 256 thr (4 waves), 512 output rows + 32 halo in LDS as bf16,
// rows exactly 128 B, phys_byte = row*128 + (col_byte ^ ((row&7)<<4)).
// Wave w owns output rows [128w, 128w+128): acc[8 mt][4 nt] of 16x16 tiles.
// Main loop: 16 tap-groups {j, j+16}; per (group, kb) a 9-step rt sweep where
// read a(rt) feeds tap j at mt=rt-1 and tap j+16 at mt=rt (8 MFMA / read).
// Tail: tap 32 alone. 2112 MFMA/wave (unchanged), 304 ds_read_b128 (was 528).
// ---------------------------------------------------------------------------
__global__ __launch_bounds__(256, 2) void k_conv(
    const float* __restrict__ u, const unsigned short* __restrict__ gG,
    const float* __restrict__ gZ, float* __restrict__ out)
{
    __shared__ __align__(16) unsigned char uS[(ROWS + HALO) * 128];  // 69,632 B
    const int tid = threadIdx.x;
    const int wv = tid >> 6, lane = tid & 63, l15 = lane & 15, q = lane >> 4;
    const int t0 = blockIdx.x * ROWS;

    // stage u rows [t0-32, t0+512) as bf16 (rows < 0 -> zeros, block 0 only)
    // thread handles one float4 -> one swizzled 8 B ds_write per iter
    {
        const float4* u4 = (const float4*)u;
        const int base4 = (t0 - HALO) * 16;     // float4 index of first staged row
#pragma unroll
        for (int e = 0; e < 34; ++e) {
            int f = e * 256 + tid;              // 8704 float4 total
            float4 v = make_float4(0.f, 0.f, 0.f, 0.f);
            if (base4 + f >= 0) v = u4[base4 + f];
            int r  = f >> 4;                    // LDS row
            int cb = (f & 15) * 8;              // col byte (8 B granule, bit3 safe)
            short4v pk;
            pk[0] = (short)f2bf(v.x); pk[1] = (short)f2bf(v.y);
            pk[2] = (short)f2bf(v.z); pk[3] = (short)f2bf(v.w);
            *(short4v*)(uS + (r * 128 + (cb ^ ((r & 7) << 4)))) = pk;
        }
    }
    __syncthreads();

    floatx4 acc[8][4];
#pragma unroll
    for (int mt = 0; mt < 8; ++mt)
#pragma unroll
        for (int nt = 0; nt < 4; ++nt) acc[mt][nt] = (floatx4){0.f, 0.f, 0.f, 0.f};

    // main loop: tap groups {j, j+16}, j = 0..15
#pragma unroll 1
    for (int j = 0; j < 16; ++j) {
        short8 b0[2][4], b1[2][4];              // taps j, j+16 (b1 used first: rt=0)
#pragma unroll
        for (int kb = 0; kb < 2; ++kb)
#pragma unroll
            for (int nt = 0; nt < 4; ++nt) {
                b1[kb][nt] = *(const short8*)(gG + (size_t)(j + 16) * 4096
                                  + (l15 + 16*nt) * 64 + kb*32 + q*8);
                b0[kb][nt] = *(const short8*)(gG + (size_t)j * 4096
                                  + (l15 + 16*nt) * 64 + kb*32 + q*8);
            }
        // LDS row for (tap j+16k, mt): wv*128 + 16*(mt-k) + (16-j) + l15
        //   rt = mt - k + 1 in [0,8];  row&7 = (l15 - j) & 7  (group-invariant)
        const int swz  = ((l15 - j) & 7) << 4;
        const int rowb = (wv * 128 + 16 - j + l15) * 128;
#pragma unroll
        for (int kb = 0; kb < 2; ++kb) {
            const int cb = (kb * 64 + q * 16) ^ swz;
#pragma unroll
            for (int rt = 0; rt <= 8; ++rt) {
                short8 a = *(const short8*)(uS + (rowb + rt * 2048 + cb));
                if (rt >= 1) {                  // tap j,   mt = rt-1
#pragma unroll
                    for (int nt = 0; nt < 4; ++nt)
                        acc[rt-1][nt] = __builtin_amdgcn_mfma_f32_16x16x32_bf16(
                            a, b0[kb][nt], acc[rt-1][nt], 0, 0, 0);
                }
                if (rt <= 7) {                  // tap j+16, mt = rt
#pragma unroll
                    for (int nt = 0; nt < 4; ++nt)
                        acc[rt][nt] = __builtin_amdgcn_mfma_f32_16x16x32_bf16(
                            a, b1[kb][nt], acc[rt][nt], 0, 0, 0);
                }
            }
        }
    }

    // tail: tap 32 (LDS row = wv*128 + 16*mt + l15)
    {
        short8 bt[2][4];
#pragma unroll
        for (int kb = 0; kb < 2; ++kb)
#pragma unroll
            for (int nt = 0; nt < 4; ++nt)
                bt[kb][nt] = *(const short8*)(gG + (size_t)32 * 4096
                                  + (l15 + 16*nt) * 64 + kb*32 + q*8);
        const int swz  = (l15 & 7) << 4;
        const int rowb = (wv * 128 + l15) * 128;
#pragma unroll
        for (int kb = 0; kb < 2; ++kb) {
            const int cb = (kb * 64 + q * 16) ^ swz;
#pragma unroll
            for (int mt = 0; mt < 8; ++mt) {
                short8 a = *(const short8*)(uS + (rowb + mt * 2048 + cb));
#pragma unroll
                for (int nt = 0; nt < 4; ++nt)
                    acc[mt][nt] = __builtin_amdgcn_mfma_f32_16x16x32_bf16(
                        a, bt[kb][nt], acc[mt][nt], 0, 0, 0);
            }
        }
    }

    // epilogue: C/D layout row = q*4+r (+16mt +128wv), col = l15 (+16nt)
    const bool zblk = (blockIdx.x == 0 && wv == 0);
#pragma unroll
    for (int mt = 0; mt < 8; ++mt)
#pragma unroll
        for (int nt = 0; nt < 4; ++nt) {
            const int p = l15 + 16*nt;
#pragma unroll
            for (int r = 0; r < 4; ++r) {
                int tl = wv*128 + mt*16 + q*4 + r;
                float v = acc[mt][nt][r];
                if (zblk && mt < 3) v += gZ[(mt*16 + q*4 + r)*64 + p];  // t < 48
                out[(size_t)(t0 + tl)*64 + p] = v;
            }
        }
}

extern "C" void kernel_launch(void* const* d_in, const int* in_sizes, int n_in,
                              void* d_out, int out_size, void* d_ws, size_t ws_size,
                              hipStream_t stream) {
    const float* u  = (const float*)d_in[0];
    const float* x0 = (const float*)d_in[1];
    const float* A  = (const float*)d_in[2];
    const float* B  = (const float*)d_in[3];
    const float* C  = (const float*)d_in[4];
    const float* D  = (const float*)d_in[5];
    float* out = (float*)d_out;

    unsigned short* gG = (unsigned short*)d_ws;                  // 33*4096 bf16 = 270 KB
    float* gZ = (float*)((char*)d_ws + 272384);                  // 48*64 fp32

    hipLaunchKernelGGL(k_prep, dim3(1), dim3(256), 0, stream,
                       A, B, C, D, x0, gG, gZ);
    hipLaunchKernelGGL(k_conv, dim3(T_LEN / ROWS), dim3(256), 0, stream,
                       u, gG, gZ, out);
}